// Round 7
// baseline (144.425 us; speedup 1.0000x reference)
//
#include <hip/hip_runtime.h>

// LinearAttention (Performer/FAVOR+): B=8, T=S=8192, F=D=64, M=128 (2M=256 features)
// R7: barrier-free LDS-free kv — each wave an independent (b, s-chunk128, featgroup64)
// item. GEMM direction flipped to C[d][feat]: A = v1^T frags gathered from global V
// (+ synthesized ones-row), B = phi(k) frags built by an 8-shuffle in-register
// transpose of the MFMA C-tiles. Partial [b][chunk][d][m] -> coalesced finalize.
//
// MFMA 16x16x32 bf16 layouts (measured, learn_hip m89/m91):
//   A-frag: lane holds A[m = lane&15][k = (lane>>4)*8 + j], j=0..7
//   B-frag: lane holds B[k = (lane>>4)*8 + j][n = lane&15]
//   C/D   : lane holds D[row = (lane>>4)*4 + reg][col = lane&15], reg=0..3

constexpr int NB = 8;
constexpr int NT = 8192;
constexpr float EPSF = 1e-9f;
constexpr float SCALE = 0.0625f;  // 1/sqrt(2*128)

typedef short s8v __attribute__((ext_vector_type(8)));
typedef short s4v __attribute__((ext_vector_type(4)));
typedef float f4v __attribute__((ext_vector_type(4)));

__device__ inline f4v mfma16(s8v a, s8v b, f4v c) {
  return __builtin_amdgcn_mfma_f32_16x16x32_bf16(a, b, c, 0, 0, 0);
}

__device__ inline short bf16_rne(float f) {
  unsigned u = __builtin_bit_cast(unsigned, f);
  u += 0x7fffu + ((u >> 16) & 1u);
  return (short)(u >> 16);
}
__device__ inline float bf16_to_f(short h) {
  unsigned u = ((unsigned)(unsigned short)h) << 16;
  return __builtin_bit_cast(float, u);
}
__device__ inline unsigned pack2(short lo, short hi) {
  return (unsigned)(unsigned short)lo | ((unsigned)(unsigned short)hi << 16);
}

// ---- setup: split omega into bf16 hi/lo (Markidis 3-term split keeps the
// pre-exp x.omega GEMM at ~fp32 accuracy) ----
__global__ void setup_omega(const float* __restrict__ omega,
                            short* __restrict__ oh, short* __restrict__ ol) {
  int i = blockIdx.x * 256 + threadIdx.x;
  if (i >= 128 * 64) return;
  float w = omega[i];
  short h = bf16_rne(w);
  oh[i] = h;
  ol[i] = bf16_rne(w - bf16_to_f(h));
}

// ---- shared phi helpers ----
struct PhiRows {
  s8v ah0, al0, ah1, al1;  // x fragments (hi/lo) for ksteps 0,1
  float ssr[4];            // |x_row|^2/2 for rows quad*4+reg (C-row indexed)
  float ss;                // |x_row|^2/2 for this lane's own row (lane&15)
};

__device__ inline void split8(f4v a, f4v b, s8v& h, s8v& l) {
  float v[8] = {a.x, a.y, a.z, a.w, b.x, b.y, b.z, b.w};
#pragma unroll
  for (int j = 0; j < 8; ++j) {
    short hh = bf16_rne(v[j]);
    h[j] = hh;
    l[j] = bf16_rne(v[j] - bf16_to_f(hh));
  }
}

__device__ inline void load_phi_rows(const float* __restrict__ xrow_base, int lane, PhiRows& P) {
  const int r = lane & 15, q = lane >> 4;
  const float* p = xrow_base + r * 64 + q * 8;
  f4v u0 = *(const f4v*)(p);
  f4v u1 = *(const f4v*)(p + 4);
  f4v u2 = *(const f4v*)(p + 32);
  f4v u3 = *(const f4v*)(p + 36);
  float ss = u0.x * u0.x + u0.y * u0.y + u0.z * u0.z + u0.w * u0.w
           + u1.x * u1.x + u1.y * u1.y + u1.z * u1.z + u1.w * u1.w
           + u2.x * u2.x + u2.y * u2.y + u2.z * u2.z + u2.w * u2.w
           + u3.x * u3.x + u3.y * u3.y + u3.z * u3.z + u3.w * u3.w;
  ss += __shfl_xor(ss, 16, 64);
  ss += __shfl_xor(ss, 32, 64);
  ss *= 0.5f;
  P.ss = ss;
#pragma unroll
  for (int reg = 0; reg < 4; ++reg) P.ssr[reg] = __shfl(ss, q * 4 + reg, 64);
  split8(u0, u1, P.ah0, P.al0);
  split8(u2, u3, P.ah1, P.al1);
}

// xw C-tile, A = x rows (C: row = x-row q*4+reg, col = omega-row lane&15)
__device__ inline f4v phi_xw_tile(const PhiRows& P, const short* __restrict__ oh,
                                  const short* __restrict__ ol, int f0, int lane) {
  const int fr = f0 + (lane & 15);
  const int q = lane >> 4;
  s8v bh0 = *(const s8v*)(oh + fr * 64 + q * 8);
  s8v bh1 = *(const s8v*)(oh + fr * 64 + 32 + q * 8);
  s8v bl0 = *(const s8v*)(ol + fr * 64 + q * 8);
  s8v bl1 = *(const s8v*)(ol + fr * 64 + 32 + q * 8);
  f4v c = {0.f, 0.f, 0.f, 0.f};
  c = mfma16(P.ah0, bh0, c);
  c = mfma16(P.ah1, bh1, c);
  c = mfma16(P.al0, bh0, c);
  c = mfma16(P.al1, bh1, c);
  c = mfma16(P.ah0, bl0, c);
  c = mfma16(P.ah1, bl1, c);
  return c;
}

// xw C-tile, swapped: A = omega rows (C: row = omega-row q*4+reg, col = x-row lane&15).
__device__ inline f4v phi_xw_tile_T(const PhiRows& P, const short* __restrict__ oh,
                                    const short* __restrict__ ol, int f0, int lane) {
  const int fr = f0 + (lane & 15);
  const int q = lane >> 4;
  s8v ah0 = *(const s8v*)(oh + fr * 64 + q * 8);
  s8v ah1 = *(const s8v*)(oh + fr * 64 + 32 + q * 8);
  s8v al0 = *(const s8v*)(ol + fr * 64 + q * 8);
  s8v al1 = *(const s8v*)(ol + fr * 64 + 32 + q * 8);
  f4v c = {0.f, 0.f, 0.f, 0.f};
  c = mfma16(ah0, P.ah0, c);
  c = mfma16(ah1, P.ah1, c);
  c = mfma16(al0, P.ah0, c);
  c = mfma16(al1, P.ah1, c);
  c = mfma16(ah0, P.al0, c);
  c = mfma16(ah1, P.al1, c);
  return c;
}

// Build a K=32 B-frag (B[k=s][n=feat]) from two 16-s phi C-tiles' packed dwords.
// gXd0/gXd1 = pack2(val[reg0],val[reg1]) / pack2(val[reg2],val[reg3]) of group X.
// Derivation: dest lane (q',r') needs s = q'*8+j from group q'>>1, source lanes
// ((q'&1)*2 + {0,1})*16 + r'. Verified lane-17 / lane-40 by hand.
__device__ inline s8v bfrag_shuffle(unsigned g0d0, unsigned g0d1,
                                    unsigned g1d0, unsigned g1d1, int lane) {
  const int sb = ((lane & 16) ? 32 : 0) | (lane & 15);
  int a0 = __shfl((int)g0d0, sb, 64);
  int a1 = __shfl((int)g0d1, sb, 64);
  int a2 = __shfl((int)g0d0, sb + 16, 64);
  int a3 = __shfl((int)g0d1, sb + 16, 64);
  int b0 = __shfl((int)g1d0, sb, 64);
  int b1 = __shfl((int)g1d1, sb, 64);
  int b2 = __shfl((int)g1d0, sb + 16, 64);
  int b3 = __shfl((int)g1d1, sb + 16, 64);
  const bool hi = lane >= 32;  // q' >= 2 -> group 1
  int4 r;
  r.x = hi ? b0 : a0;
  r.y = hi ? b1 : a1;
  r.z = hi ? b2 : a2;
  r.w = hi ? b3 : a3;
  return __builtin_bit_cast(s8v, r);
}

// ---- Kernel KV: wave-independent fused phi(k) + kv GEMM. ----
// 2048 waves (1024 blocks x 128 thr): wave = (b, chunk of 128 s, fg of 64 feats).
// fg covers omega rows [fg*32, fg*32+32) x both signs. No LDS, no barriers.
// partial[b][chunk 64][d 65][m 256] bf16.
__global__ __launch_bounds__(128, 2) void kv_wave(
    const float* __restrict__ key, const float* __restrict__ value,
    const short* __restrict__ oh, const short* __restrict__ ol,
    short* __restrict__ partial, float* __restrict__ kvacc, int use_partial) {
  const int lane = threadIdx.x & 63;
  const int wid = blockIdx.x * 2 + (threadIdx.x >> 6);  // 0..2047
  const int b = wid >> 8;
  const int rem = wid & 255;
  const int chunk = rem >> 2, fg = rem & 3;
  const int q = lane >> 4, r15 = lane & 15;

  f4v acc[5][4];  // [m-tile d][n-tile feat]
#pragma unroll
  for (int mt = 0; mt < 5; ++mt)
#pragma unroll
    for (int n = 0; n < 4; ++n) acc[mt][n] = f4v{0.f, 0.f, 0.f, 0.f};

  // ones-row A-frag for m-tile 4 (d=64 -> 1.0, d=65..79 -> 0)
  s8v a4;
  {
    short v = (r15 == 0) ? (short)0x3F80 : (short)0;
#pragma unroll
    for (int j = 0; j < 8; ++j) a4[j] = v;
  }

  for (int sub = 0; sub < 4; ++sub) {
    const int sB = chunk * 128 + sub * 32;
    PhiRows P0, P1;
    load_phi_rows(key + ((size_t)b * NT + sB) * 64, lane, P0);
    load_phi_rows(key + ((size_t)b * NT + sB + 16) * 64, lane, P1);
    // A-frags: lane holds A[m = mt*16+r15][k = s-local q*8+j] = bf16(V[sB+q*8+j][d])
    s8v aF[4];
#pragma unroll
    for (int mt = 0; mt < 4; ++mt) {
      const float* vp = value + ((size_t)b * NT + sB + q * 8) * 64 + mt * 16 + r15;
#pragma unroll
      for (int j = 0; j < 8; ++j) aF[mt][j] = bf16_rne(vp[j * 64]);
    }
#pragma unroll
    for (int ot = 0; ot < 2; ++ot) {
      const int f0 = fg * 32 + ot * 16;
      f4v c0 = phi_xw_tile(P0, oh, ol, f0, lane);
      f4v c1 = phi_xw_tile(P1, oh, ol, f0, lane);
      short p0s[4], n0s[4], p1s[4], n1s[4];
#pragma unroll
      for (int reg = 0; reg < 4; ++reg) {
        float x0 = c0[reg], x1 = c1[reg];
        p0s[reg] = bf16_rne((__expf(x0 - P0.ssr[reg]) + EPSF) * SCALE);
        n0s[reg] = bf16_rne((__expf(-x0 - P0.ssr[reg]) + EPSF) * SCALE);
        p1s[reg] = bf16_rne((__expf(x1 - P1.ssr[reg]) + EPSF) * SCALE);
        n1s[reg] = bf16_rne((__expf(-x1 - P1.ssr[reg]) + EPSF) * SCALE);
      }
      // plus-sign B-frag -> acc[. ][ot]; minus-sign -> acc[.][2+ot]
      {
        s8v bF = bfrag_shuffle(pack2(p0s[0], p0s[1]), pack2(p0s[2], p0s[3]),
                               pack2(p1s[0], p1s[1]), pack2(p1s[2], p1s[3]), lane);
#pragma unroll
        for (int mt = 0; mt < 4; ++mt) acc[mt][ot] = mfma16(aF[mt], bF, acc[mt][ot]);
        acc[4][ot] = mfma16(a4, bF, acc[4][ot]);
      }
      {
        s8v bF = bfrag_shuffle(pack2(n0s[0], n0s[1]), pack2(n0s[2], n0s[3]),
                               pack2(n1s[0], n1s[1]), pack2(n1s[2], n1s[3]), lane);
#pragma unroll
        for (int mt = 0; mt < 4; ++mt) acc[mt][2 + ot] = mfma16(aF[mt], bF, acc[mt][2 + ot]);
        acc[4][2 + ot] = mfma16(a4, bF, acc[4][2 + ot]);
      }
    }
  }
  // epilogue: C row = d (mt*16+q*4+reg), col = feat n*... -> partial[b][chunk][d][m]
  if (use_partial) {
    short* pb = partial + ((size_t)(b * 64 + chunk) * 65) * 256;
#pragma unroll
    for (int n = 0; n < 4; ++n) {
      const int m = ((n & 2) ? 128 : 0) + fg * 32 + (n & 1) * 16 + r15;
#pragma unroll
      for (int mt = 0; mt < 4; ++mt)
#pragma unroll
        for (int reg = 0; reg < 4; ++reg) {
          int d = mt * 16 + q * 4 + reg;
          pb[d * 256 + m] = bf16_rne(acc[mt][n][reg]);
        }
      if (q == 0) pb[64 * 256 + m] = bf16_rne(acc[4][n][0]);  // d=64 row
    }
  } else {
    float* pb = kvacc + (size_t)b * (65 * 256);
#pragma unroll
    for (int n = 0; n < 4; ++n) {
      const int m = ((n & 2) ? 128 : 0) + fg * 32 + (n & 1) * 16 + r15;
#pragma unroll
      for (int mt = 0; mt < 4; ++mt)
#pragma unroll
        for (int reg = 0; reg < 4; ++reg) {
          int d = mt * 16 + q * 4 + reg;
          atomicAdd(pb + d * 256 + m, acc[mt][n][reg]);
        }
      if (q == 0) atomicAdd(pb + 64 * 256 + m, acc[4][n][0]);
    }
  }
}

// ---- Kernel finalize: reduce bf16 partials -> kvfrag (B-fragment order) ----
// kvfrag[b][fid=ks*5+n][lane][j]: lane holds B[k=ks*32+(lane>>4)*8+j][d=n*16+(lane&15)]
// Partial reads are fully coalesced: lanes span m at fixed (b, chunk, d).
__global__ __launch_bounds__(256) void kv_finalize(
    const short* __restrict__ partial, const float* __restrict__ kvacc,
    short* __restrict__ kvfrag, int use_partial) {
  int i = blockIdx.x * 256 + threadIdx.x;  // 163840 outputs: (b, d=0..79, m)
  int b = i / 20480;
  int rem = i - b * 20480;
  int d = rem >> 8;
  int m = rem & 255;
  float s = 0.f;
  if (d < 65) {
    if (use_partial) {
      const short* p = partial + ((size_t)(b * 64) * 65 + d) * 256 + m;
#pragma unroll 8
      for (int c = 0; c < 64; ++c) s += bf16_to_f(p[(size_t)c * (65 * 256)]);
    } else {
      s = kvacc[((size_t)b * 65 + d) * 256 + m];
    }
  }
  int ks = m >> 5, qq = (m >> 3) & 3, j = m & 7;
  int n = d >> 4, r = d & 15;
  int lane = qq * 16 + r;
  kvfrag[(((size_t)b * 40 + ks * 5 + n) * 64 + lane) * 8 + j] = bf16_rne(s);
}

// ---- Kernel QKV: fused phi(q) + qkv GEMM + normalize (unchanged from R6) ----
// grid 1024 = 8b x 128 t-chunks(64). qf is wave-private -> no barriers.
constexpr int QF_P = 264;  // qf pitch (shorts): 256 + 8 pad
__global__ __launch_bounds__(256, 4) void qkv_fused(
    const float* __restrict__ query, const short* __restrict__ oh,
    const short* __restrict__ ol, const short* __restrict__ kvfrag,
    float* __restrict__ out) {
  __shared__ __align__(16) short qf[64 * QF_P];  // [t][feat] bf16, 33792 B
  const int tid = threadIdx.x, lane = tid & 63, w = tid >> 6;
  const int b = blockIdx.x >> 7;
  const int t0 = (blockIdx.x & 127) * 64;
  const int q = lane >> 4, r15 = lane & 15;

  // phi(q), swapped operands: C row = omega-row, col = t -> packed s4v writes
  {
    PhiRows P;
    load_phi_rows(query + ((size_t)b * NT + t0 + w * 16) * 64, lane, P);
    const int t_loc = w * 16 + r15;
#pragma unroll
    for (int ft = 0; ft < 8; ++ft) {
      f4v c = phi_xw_tile_T(P, oh, ol, ft * 16, lane);
      s4v pk, nk;
#pragma unroll
      for (int reg = 0; reg < 4; ++reg) {
        float xw = c[reg];  // feature ft*16+q*4+reg for x-row r15 (own ss)
        pk[reg] = bf16_rne((__expf(xw - P.ss) + EPSF) * SCALE);
        nk[reg] = bf16_rne((__expf(-xw - P.ss) + EPSF) * SCALE);
      }
      *(s4v*)(qf + t_loc * QF_P + ft * 16 + q * 4) = pk;
      *(s4v*)(qf + t_loc * QF_P + 128 + ft * 16 + q * 4) = nk;
    }
  }
  // GEMM: wave w's A rows = its own 16 t-rows; B-frags straight from global (L2)
  f4v acc[5];
#pragma unroll
  for (int n = 0; n < 5; ++n) acc[n] = f4v{0.f, 0.f, 0.f, 0.f};
  const short* kvb = kvfrag + (size_t)b * 40 * 512;
#pragma unroll
  for (int ks = 0; ks < 8; ++ks) {
    s8v a = *(const s8v*)(qf + (w * 16 + r15) * QF_P + ks * 32 + q * 8);
#pragma unroll
    for (int n = 0; n < 5; ++n) {
      s8v bf = *(const s8v*)(kvb + ((size_t)(ks * 5 + n)) * 512 + lane * 8);
      acc[n] = mfma16(a, bf, acc[n]);
    }
  }
  // denominator: N-tile 4 col 0 (d=64) holds den for rows q*4+reg
  float den_r[4];
#pragma unroll
  for (int reg = 0; reg < 4; ++reg) den_r[reg] = __shfl(acc[4][reg], lane & 48, 64);
  // normalize + stage into this wave's own qf region (its A-reads are done)
  float* stg = (float*)(qf + w * 16 * QF_P);  // 16x68 f32 = 4352 B < 8448 B region
#pragma unroll
  for (int n = 0; n < 4; ++n)
#pragma unroll
    for (int reg = 0; reg < 4; ++reg) {
      int row = q * 4 + reg;
      int col = n * 16 + r15;
      stg[row * 68 + col] = acc[n][reg] / den_r[reg];
    }
  // coalesced copy out (wave-private)
  float* ob = out + ((size_t)b * NT + t0 + w * 16) * 64;
#pragma unroll
  for (int rr = 0; rr < 4; ++rr) {
    int row = rr * 4 + q;
    int c4 = r15 * 4;
    *(f4v*)(ob + row * 64 + c4) = *(const f4v*)(stg + row * 68 + c4);
  }
}

extern "C" void kernel_launch(void* const* d_in, const int* in_sizes, int n_in,
                              void* d_out, int out_size, void* d_ws, size_t ws_size,
                              hipStream_t stream) {
  const float* query = (const float*)d_in[0];  // [8][8192][64]
  const float* value = (const float*)d_in[1];  // [8][8192][64]
  const float* key   = (const float*)d_in[2];  // [8][8192][64]
  const float* omega = (const float*)d_in[3];  // [128][64]
  float* out = (float*)d_out;

  char* ws = (char*)d_ws;
  short* oh = (short*)ws;                        // 16384 B
  short* ol = (short*)(ws + 16384);              // 16384 B
  short* kvfrag = (short*)(ws + 32768);          // 8*40*512*2 = 327680 B
  short* partial = (short*)(ws + 360448);        // 8*64*65*256*2 = 17039360 B
  float* kvacc = (float*)(ws + 360448);          // fallback: 8*65*256*4 = 532480 B
  const size_t need_full = 360448 + (size_t)NB * 64 * 65 * 256 * 2;  // ~17.4 MB
  const int use_partial = (ws_size >= need_full) ? 1 : 0;

  setup_omega<<<32, 256, 0, stream>>>(omega, oh, ol);
  if (!use_partial) {
    hipMemsetAsync(kvacc, 0, (size_t)NB * 65 * 256 * 4, stream);  // atomic targets
  }
  kv_wave<<<1024, 128, 0, stream>>>(key, value, oh, ol, partial, kvacc, use_partial);
  kv_finalize<<<640, 256, 0, stream>>>(partial, kvacc, kvfrag, use_partial);
  qkv_fused<<<1024, 256, 0, stream>>>(query, oh, ol, kvfrag, out);
}

// Round 8
// 143.912 us; speedup vs baseline: 1.0036x; 1.0036x over previous
//
#include <hip/hip_runtime.h>

// LinearAttention (Performer/FAVOR+): B=8, T=S=8192, F=D=64, M=128 (2M=256 features)
// R8: qkv critical-path fix — in-register transpose (bfrag_shuffle) replaces the
// qf LDS round-trip; LDS halves to 17.4 KB (output staging only); per-k-step-pair
// fusion keeps live registers low. kv/finalize = R6 (lowest-traffic proven).
//
// MFMA 16x16x32 bf16 layouts (measured, learn_hip m89/m91):
//   A-frag: lane holds A[m = lane&15][k = (lane>>4)*8 + j], j=0..7
//   B-frag: lane holds B[k = (lane>>4)*8 + j][n = lane&15]
//   C/D   : lane holds D[row = (lane>>4)*4 + reg][col = lane&15], reg=0..3

constexpr int NB = 8;
constexpr int NT = 8192;
constexpr float EPSF = 1e-9f;
constexpr float SCALE = 0.0625f;  // 1/sqrt(2*128)

typedef short s8v __attribute__((ext_vector_type(8)));
typedef short s4v __attribute__((ext_vector_type(4)));
typedef float f4v __attribute__((ext_vector_type(4)));

__device__ inline f4v mfma16(s8v a, s8v b, f4v c) {
  return __builtin_amdgcn_mfma_f32_16x16x32_bf16(a, b, c, 0, 0, 0);
}

__device__ inline short bf16_rne(float f) {
  unsigned u = __builtin_bit_cast(unsigned, f);
  u += 0x7fffu + ((u >> 16) & 1u);
  return (short)(u >> 16);
}
__device__ inline float bf16_to_f(short h) {
  unsigned u = ((unsigned)(unsigned short)h) << 16;
  return __builtin_bit_cast(float, u);
}
__device__ inline unsigned pack2(short lo, short hi) {
  return (unsigned)(unsigned short)lo | ((unsigned)(unsigned short)hi << 16);
}

// ---- setup: split omega into bf16 hi/lo (Markidis 3-term split keeps the
// pre-exp x.omega GEMM at ~fp32 accuracy) ----
__global__ void setup_omega(const float* __restrict__ omega,
                            short* __restrict__ oh, short* __restrict__ ol) {
  int i = blockIdx.x * 256 + threadIdx.x;
  if (i >= 128 * 64) return;
  float w = omega[i];
  short h = bf16_rne(w);
  oh[i] = h;
  ol[i] = bf16_rne(w - bf16_to_f(h));
}

// ---- shared phi helpers ----
struct PhiRows {
  s8v ah0, al0, ah1, al1;  // x fragments (hi/lo) for ksteps 0,1
  float ssr[4];            // |x_row|^2/2 for rows quad*4+reg (C-row indexed)
  float ss;                // |x_row|^2/2 for this lane's own row (lane&15)
};

__device__ inline void split8(f4v a, f4v b, s8v& h, s8v& l) {
  float v[8] = {a.x, a.y, a.z, a.w, b.x, b.y, b.z, b.w};
#pragma unroll
  for (int j = 0; j < 8; ++j) {
    short hh = bf16_rne(v[j]);
    h[j] = hh;
    l[j] = bf16_rne(v[j] - bf16_to_f(hh));
  }
}

__device__ inline void load_phi_rows(const float* __restrict__ xrow_base, int lane, PhiRows& P) {
  const int r = lane & 15, q = lane >> 4;
  const float* p = xrow_base + r * 64 + q * 8;
  f4v u0 = *(const f4v*)(p);
  f4v u1 = *(const f4v*)(p + 4);
  f4v u2 = *(const f4v*)(p + 32);
  f4v u3 = *(const f4v*)(p + 36);
  float ss = u0.x * u0.x + u0.y * u0.y + u0.z * u0.z + u0.w * u0.w
           + u1.x * u1.x + u1.y * u1.y + u1.z * u1.z + u1.w * u1.w
           + u2.x * u2.x + u2.y * u2.y + u2.z * u2.z + u2.w * u2.w
           + u3.x * u3.x + u3.y * u3.y + u3.z * u3.z + u3.w * u3.w;
  ss += __shfl_xor(ss, 16, 64);
  ss += __shfl_xor(ss, 32, 64);
  ss *= 0.5f;
  P.ss = ss;
#pragma unroll
  for (int reg = 0; reg < 4; ++reg) P.ssr[reg] = __shfl(ss, q * 4 + reg, 64);
  split8(u0, u1, P.ah0, P.al0);
  split8(u2, u3, P.ah1, P.al1);
}

// xw C-tile, A = x rows (C: row = x-row q*4+reg, col = omega-row lane&15)
__device__ inline f4v phi_xw_tile(const PhiRows& P, const short* __restrict__ oh,
                                  const short* __restrict__ ol, int f0, int lane) {
  const int fr = f0 + (lane & 15);
  const int q = lane >> 4;
  s8v bh0 = *(const s8v*)(oh + fr * 64 + q * 8);
  s8v bh1 = *(const s8v*)(oh + fr * 64 + 32 + q * 8);
  s8v bl0 = *(const s8v*)(ol + fr * 64 + q * 8);
  s8v bl1 = *(const s8v*)(ol + fr * 64 + 32 + q * 8);
  f4v c = {0.f, 0.f, 0.f, 0.f};
  c = mfma16(P.ah0, bh0, c);
  c = mfma16(P.ah1, bh1, c);
  c = mfma16(P.al0, bh0, c);
  c = mfma16(P.al1, bh1, c);
  c = mfma16(P.ah0, bl0, c);
  c = mfma16(P.ah1, bl1, c);
  return c;
}

// xw C-tile, swapped: A = omega rows (C: row = omega-row q*4+reg, col = x-row lane&15).
__device__ inline f4v phi_xw_tile_T(const PhiRows& P, const short* __restrict__ oh,
                                    const short* __restrict__ ol, int f0, int lane) {
  const int fr = f0 + (lane & 15);
  const int q = lane >> 4;
  s8v ah0 = *(const s8v*)(oh + fr * 64 + q * 8);
  s8v ah1 = *(const s8v*)(oh + fr * 64 + 32 + q * 8);
  s8v al0 = *(const s8v*)(ol + fr * 64 + q * 8);
  s8v al1 = *(const s8v*)(ol + fr * 64 + 32 + q * 8);
  f4v c = {0.f, 0.f, 0.f, 0.f};
  c = mfma16(ah0, P.ah0, c);
  c = mfma16(ah1, P.ah1, c);
  c = mfma16(al0, P.ah0, c);
  c = mfma16(al1, P.ah1, c);
  c = mfma16(ah0, P.al0, c);
  c = mfma16(ah1, P.al1, c);
  return c;
}

// Convert two 16-row C-tiles (row = k-local q*4+reg, col = n r15) into one K=32
// B-layout frag: lane (q',r') holds val[k = q'*8+j][n = r']. Group0 supplies
// k 0..15, group1 k 16..31. gXd0 = pack2(val[reg0],val[reg1]), gXd1 = pack2(r2,r3).
// (HW-verified by R7 kv passing with this transform in the kf path.)
__device__ inline s8v bfrag_shuffle(unsigned g0d0, unsigned g0d1,
                                    unsigned g1d0, unsigned g1d1, int lane) {
  const int sb = ((lane & 16) ? 32 : 0) | (lane & 15);
  int a0 = __shfl((int)g0d0, sb, 64);
  int a1 = __shfl((int)g0d1, sb, 64);
  int a2 = __shfl((int)g0d0, sb + 16, 64);
  int a3 = __shfl((int)g0d1, sb + 16, 64);
  int b0 = __shfl((int)g1d0, sb, 64);
  int b1 = __shfl((int)g1d1, sb, 64);
  int b2 = __shfl((int)g1d0, sb + 16, 64);
  int b3 = __shfl((int)g1d1, sb + 16, 64);
  const bool hi = lane >= 32;
  int4 r;
  r.x = hi ? b0 : a0;
  r.y = hi ? b1 : a1;
  r.z = hi ? b2 : a2;
  r.w = hi ? b3 : a3;
  return __builtin_bit_cast(s8v, r);
}

constexpr int KF_P = 72;          // kft/v1t pitch in shorts
constexpr int PART_SZ = 65 * 256; // trimmed partial tile

// ---- Kernel KV: fused phi(k) + kv GEMM, full 256 features per block (R6) ----
// grid 512 = 8b x 64 s-chunks(128). partial[blk][d=0..64][m=0..255] bf16 -> 17 MB.
__global__ __launch_bounds__(256, 2) void kv_fused(
    const float* __restrict__ key, const float* __restrict__ value,
    const short* __restrict__ oh, const short* __restrict__ ol,
    short* __restrict__ partial, float* __restrict__ kvacc, int use_partial) {
  __shared__ short kft[256 * KF_P];  // [feat][s] bf16, 36864 B
  __shared__ short v1t[80 * KF_P];   // [d][s] bf16, 11520 B
  const int tid = threadIdx.x, lane = tid & 63, w = tid >> 6;
  const int b = blockIdx.x >> 6;
  const int s0 = (blockIdx.x & 63) * 128;
  const int q = lane >> 4, r15 = lane & 15;

  for (int i = tid; i < 15 * KF_P; i += 256) v1t[65 * KF_P + i] = 0;

  f4v acc[4][5];
#pragma unroll
  for (int j = 0; j < 4; ++j)
#pragma unroll
    for (int n = 0; n < 5; ++n) acc[j][n] = f4v{0.f, 0.f, 0.f, 0.f};

  for (int sc = 0; sc < 2; ++sc) {
    const int sbase = s0 + sc * 64;
    __syncthreads();
    {
      const float* vb = value + ((size_t)b * NT + sbase) * 64;
#pragma unroll
      for (int i = 0; i < 4; ++i) {
        int e4 = tid + i * 256;
        f4v v4 = ((const f4v*)vb)[e4];
        int s = e4 >> 4, d0 = (e4 & 15) * 4;
        v1t[(d0 + 0) * KF_P + s] = bf16_rne(v4.x);
        v1t[(d0 + 1) * KF_P + s] = bf16_rne(v4.y);
        v1t[(d0 + 2) * KF_P + s] = bf16_rne(v4.z);
        v1t[(d0 + 3) * KF_P + s] = bf16_rne(v4.w);
      }
      if (tid < 64) v1t[64 * KF_P + tid] = (short)0x3F80;  // bf16(1.0)
    }
    {
      PhiRows P;
      load_phi_rows(key + ((size_t)b * NT + sbase + w * 16) * 64, lane, P);
#pragma unroll
      for (int ft = 0; ft < 8; ++ft) {
        f4v c = phi_xw_tile(P, oh, ol, ft * 16, lane);
        s4v pk, nk;
#pragma unroll
        for (int reg = 0; reg < 4; ++reg) {
          float xw = c[reg];
          pk[reg] = bf16_rne((__expf(xw - P.ssr[reg]) + EPSF) * SCALE);
          nk[reg] = bf16_rne((__expf(-xw - P.ssr[reg]) + EPSF) * SCALE);
        }
        const int scol = w * 16 + q * 4;
        *(s4v*)(kft + (ft * 16 + r15) * KF_P + scol) = pk;
        *(s4v*)(kft + (128 + ft * 16 + r15) * KF_P + scol) = nk;
      }
    }
    __syncthreads();
#pragma unroll
    for (int ks = 0; ks < 2; ++ks) {
      s8v bf[5];
#pragma unroll
      for (int n = 0; n < 5; ++n)
        bf[n] = *(const s8v*)(v1t + (n * 16 + r15) * KF_P + ks * 32 + q * 8);
#pragma unroll
      for (int j = 0; j < 4; ++j) {
        s8v a = *(const s8v*)(kft + (w * 64 + j * 16 + r15) * KF_P + ks * 32 + q * 8);
#pragma unroll
        for (int n = 0; n < 5; ++n) acc[j][n] = mfma16(a, bf[n], acc[j][n]);
      }
    }
  }
  if (use_partial) {
    short* pb = partial + (size_t)blockIdx.x * PART_SZ;
#pragma unroll
    for (int j = 0; j < 4; ++j) {
      int m = w * 64 + j * 16 + q * 4;
#pragma unroll
      for (int n = 0; n < 4; ++n) {
        int d = n * 16 + r15;
        s4v pk;
#pragma unroll
        for (int reg = 0; reg < 4; ++reg) pk[reg] = bf16_rne(acc[j][n][reg]);
        *(s4v*)(pb + d * 256 + m) = pk;
      }
      if (r15 == 0) {
        s4v pk;
#pragma unroll
        for (int reg = 0; reg < 4; ++reg) pk[reg] = bf16_rne(acc[j][4][reg]);
        *(s4v*)(pb + 64 * 256 + m) = pk;
      }
    }
  } else {
    float* pb = kvacc + (size_t)b * PART_SZ;
#pragma unroll
    for (int j = 0; j < 4; ++j) {
      int m = w * 64 + j * 16 + q * 4;
#pragma unroll
      for (int n = 0; n < 4; ++n) {
        int d = n * 16 + r15;
#pragma unroll
        for (int reg = 0; reg < 4; ++reg) atomicAdd(pb + d * 256 + m + reg, acc[j][n][reg]);
      }
      if (r15 == 0)
#pragma unroll
        for (int reg = 0; reg < 4; ++reg) atomicAdd(pb + 64 * 256 + m + reg, acc[j][4][reg]);
    }
  }
}

// ---- Kernel finalize: reduce bf16 partials -> kvfrag (B-fragment order) ----
__global__ __launch_bounds__(256) void kv_finalize(
    const short* __restrict__ partial, const float* __restrict__ kvacc,
    short* __restrict__ kvfrag, int use_partial) {
  int i = blockIdx.x * 256 + threadIdx.x;  // 163840 outputs: (b, d=0..79, m)
  int b = i / 20480;
  int rem = i - b * 20480;
  int d = rem >> 8;
  int m = rem & 255;
  float s = 0.f;
  if (d < 65) {
    if (use_partial) {
      const short* p = partial + (size_t)(b * 64) * PART_SZ + d * 256 + m;
#pragma unroll 8
      for (int c = 0; c < 64; ++c) s += bf16_to_f(p[(size_t)c * PART_SZ]);
    } else {
      s = kvacc[(size_t)b * PART_SZ + d * 256 + m];
    }
  }
  int ks = m >> 5, qq = (m >> 3) & 3, j = m & 7;
  int n = d >> 4, r = d & 15;
  int lane = qq * 16 + r;
  kvfrag[(((size_t)b * 40 + ks * 5 + n) * 64 + lane) * 8 + j] = bf16_rne(s);
}

// ---- Kernel QKV (R8): phi(q) -> in-register transpose -> GEMM -> normalize ----
// grid 1024 = 8b x 128 t-chunks(64). No LDS in the compute path; LDS only for
// wave-private output staging (17.4 KB). Per k-step-pair kp: compute phi_T tiles
// 2kp,2kp+1 -> bfrag_shuffle gives A-frags (plus feats -> ks=kp, minus -> kp+4)
// -> GEMM both immediately. Only one tile-pair's values live at a time.
__global__ __launch_bounds__(256, 4) void qkv_fused(
    const float* __restrict__ query, const short* __restrict__ oh,
    const short* __restrict__ ol, const short* __restrict__ kvfrag,
    float* __restrict__ out) {
  __shared__ __align__(16) float stg[4][16 * 68];  // 17408 B, wave-private
  const int tid = threadIdx.x, lane = tid & 63, w = tid >> 6;
  const int b = blockIdx.x >> 7;
  const int t0 = (blockIdx.x & 127) * 64;
  const int q = lane >> 4, r15 = lane & 15;

  PhiRows P;
  load_phi_rows(query + ((size_t)b * NT + t0 + w * 16) * 64, lane, P);

  f4v acc[5];
#pragma unroll
  for (int n = 0; n < 5; ++n) acc[n] = f4v{0.f, 0.f, 0.f, 0.f};
  const short* kvb = kvfrag + (size_t)b * 40 * 512;

#pragma unroll
  for (int kp = 0; kp < 4; ++kp) {
    // phi_T tiles covering plus-feats kp*32..+15 and +16..+31 (col = t-local r15)
    f4v c0 = phi_xw_tile_T(P, oh, ol, kp * 32, lane);
    f4v c1 = phi_xw_tile_T(P, oh, ol, kp * 32 + 16, lane);
    short p0[4], n0[4], p1[4], n1[4];
#pragma unroll
    for (int reg = 0; reg < 4; ++reg) {
      float x0 = c0[reg], x1 = c1[reg];
      p0[reg] = bf16_rne((__expf(x0 - P.ss) + EPSF) * SCALE);
      n0[reg] = bf16_rne((__expf(-x0 - P.ss) + EPSF) * SCALE);
      p1[reg] = bf16_rne((__expf(x1 - P.ss) + EPSF) * SCALE);
      n1[reg] = bf16_rne((__expf(-x1 - P.ss) + EPSF) * SCALE);
    }
    // A-frag for k-step kp (plus feats m = kp*32 + k-local): lane holds
    // qf[t=r15][m], exactly the A[m=t][k] fragment layout.
    {
      s8v aP = bfrag_shuffle(pack2(p0[0], p0[1]), pack2(p0[2], p0[3]),
                             pack2(p1[0], p1[1]), pack2(p1[2], p1[3]), lane);
#pragma unroll
      for (int n = 0; n < 5; ++n) {
        s8v bf = *(const s8v*)(kvb + ((size_t)(kp * 5 + n)) * 512 + lane * 8);
        acc[n] = mfma16(aP, bf, acc[n]);
      }
    }
    // A-frag for k-step kp+4 (minus feats m = 128 + kp*32 + k-local)
    {
      s8v aN = bfrag_shuffle(pack2(n0[0], n0[1]), pack2(n0[2], n0[3]),
                             pack2(n1[0], n1[1]), pack2(n1[2], n1[3]), lane);
#pragma unroll
      for (int n = 0; n < 5; ++n) {
        s8v bf = *(const s8v*)(kvb + ((size_t)((kp + 4) * 5 + n)) * 512 + lane * 8);
        acc[n] = mfma16(aN, bf, acc[n]);
      }
    }
  }
  // denominator: N-tile 4 col 0 (d=64) holds den for t-rows q*4+reg
  float den_r[4];
#pragma unroll
  for (int reg = 0; reg < 4; ++reg) den_r[reg] = __shfl(acc[4][reg], lane & 48, 64);
  // normalize + wave-private staging (no barrier: same-wave LDS ordering)
  float* sg = stg[w];
#pragma unroll
  for (int n = 0; n < 4; ++n)
#pragma unroll
    for (int reg = 0; reg < 4; ++reg) {
      int row = q * 4 + reg;
      int col = n * 16 + r15;
      sg[row * 68 + col] = acc[n][reg] / den_r[reg];
    }
  // coalesced copy out
  float* ob = out + ((size_t)b * NT + t0 + w * 16) * 64;
#pragma unroll
  for (int rr = 0; rr < 4; ++rr) {
    int row = rr * 4 + q;
    int c4 = r15 * 4;
    *(f4v*)(ob + row * 64 + c4) = *(const f4v*)(sg + row * 68 + c4);
  }
}

extern "C" void kernel_launch(void* const* d_in, const int* in_sizes, int n_in,
                              void* d_out, int out_size, void* d_ws, size_t ws_size,
                              hipStream_t stream) {
  const float* query = (const float*)d_in[0];  // [8][8192][64]
  const float* value = (const float*)d_in[1];  // [8][8192][64]
  const float* key   = (const float*)d_in[2];  // [8][8192][64]
  const float* omega = (const float*)d_in[3];  // [128][64]
  float* out = (float*)d_out;

  char* ws = (char*)d_ws;
  short* oh = (short*)ws;                        // 16384 B
  short* ol = (short*)(ws + 16384);              // 16384 B
  short* kvfrag = (short*)(ws + 32768);          // 8*40*512*2 = 327680 B
  short* partial = (short*)(ws + 360448);        // 512*65*256*2 = 17039360 B
  float* kvacc = (float*)(ws + 360448);          // fallback: 8*65*256*4 = 532480 B
  const size_t need_full = 360448 + (size_t)512 * PART_SZ * 2;  // ~17.4 MB
  const int use_partial = (ws_size >= need_full) ? 1 : 0;

  setup_omega<<<32, 256, 0, stream>>>(omega, oh, ol);
  if (!use_partial) {
    hipMemsetAsync(kvacc, 0, (size_t)8 * PART_SZ * 4, stream);  // atomic targets
  }
  kv_fused<<<512, 256, 0, stream>>>(key, value, oh, ol, partial, kvacc, use_partial);
  kv_finalize<<<640, 256, 0, stream>>>(partial, kvacc, kvfrag, use_partial);
  qkv_fused<<<1024, 256, 0, stream>>>(query, oh, ol, kvfrag, out);
}